// Round 1
// baseline (360.682 us; speedup 1.0000x reference)
//
#include <hip/hip_runtime.h>
#include <hip/hip_bf16.h>
#include <cmath>

// Problem constants (fixed by the reference):
// x: [B=4,S=2,P=1024,D=1024] f32; W_{K,Q,V}: [S,I=16,H=64,D] f32; W_O: [S,D,I*H] f32
// out: [B,S,P,D] f32
#define Bc 4
#define Sc 2
#define Pc 1024
#define Dc 1024
#define Ic 16
#define Hc 64

typedef unsigned short u16;
typedef __attribute__((ext_vector_type(8))) short short8;
typedef __attribute__((ext_vector_type(8))) __bf16 bf16x8;
typedef __attribute__((ext_vector_type(4))) float f32x4;

__device__ __forceinline__ u16 f2bf(float f) {
  union { float f; unsigned u; } c; c.f = f;
  unsigned u = c.u;
  u += 0x7fffu + ((u >> 16) & 1u);   // RNE
  return (u16)(u >> 16);
}

__device__ __forceinline__ f32x4 mfma16(short8 a, short8 b, f32x4 c) {
  return __builtin_amdgcn_mfma_f32_16x16x32_bf16(
      __builtin_bit_cast(bf16x8, a), __builtin_bit_cast(bf16x8, b), c, 0, 0, 0);
}

__device__ __forceinline__ void load_lds16(const u16* g, u16* l) {
  __builtin_amdgcn_global_load_lds(
      (const __attribute__((address_space(1))) void*)g,
      (__attribute__((address_space(3))) void*)l, 16, 0, 0);
}

// ---------------- fp32 -> bf16 convert ----------------
__global__ void cvt_kernel(const float* __restrict__ src, u16* __restrict__ dst, int n4) {
  int i = blockIdx.x * blockDim.x + threadIdx.x;
  int stride = gridDim.x * blockDim.x;
  for (; i < n4; i += stride) {
    float4 v = reinterpret_cast<const float4*>(src)[i];
    ushort4 o;
    o.x = f2bf(v.x); o.y = f2bf(v.y); o.z = f2bf(v.z); o.w = f2bf(v.w);
    reinterpret_cast<ushort4*>(dst)[i] = o;
  }
}

// ---------------- GEMM-BT: C[M=1024,N=1024] = A[bs] * B[s]^T (K=1024) ----------------
// A: bf16 [8][1024][1024] row-major (K contiguous). B: bf16 [2][1024][1024] (K contiguous).
// MODE 0: dst bf16 heads layout [bs*16 + n>>6][p][n&63]   (Q, K)
// MODE 1: dst bf16 transposed   [bs*16 + n>>6][n&63][p]   (V^T)
// MODE 2: dst f32  [bs][p][n]                              (final out)
template<int MODE>
__global__ __launch_bounds__(256)
void gemm_bt(const u16* __restrict__ A, const u16* __restrict__ Bm, void* __restrict__ C) {
  __shared__ u16 As[128 * 32];
  __shared__ u16 Bs[128 * 32];
  const int tid = threadIdx.x;
  const int lane = tid & 63;
  const int wv = tid >> 6;
  const int wr = wv >> 1, wc = wv & 1;
  const int lr = lane & 15, lg = lane >> 4;
  const int m0 = blockIdx.x * 128, n0 = blockIdx.y * 128;
  const int bs = blockIdx.z;
  const u16* Ab = A + (size_t)bs * (Pc * Dc);
  const u16* Bb = Bm + (size_t)(bs & 1) * (1024 * 1024);
  f32x4 acc[4][4] = {};

  for (int k0 = 0; k0 < 1024; k0 += 32) {
#pragma unroll
    for (int it = 0; it < 2; ++it) {
      int slot = it * 256 + tid;
      int row = slot >> 2;
      int c8 = (slot & 3) << 3;
      load_lds16(Ab + (size_t)(m0 + row) * 1024 + k0 + c8, As + slot * 8);
      load_lds16(Bb + (size_t)(n0 + row) * 1024 + k0 + c8, Bs + slot * 8);
    }
    __syncthreads();   // drains vmcnt -> LDS staged
    short8 af[4], bfr[4];
#pragma unroll
    for (int m = 0; m < 4; ++m)
      af[m] = *reinterpret_cast<const short8*>(&As[(wr * 64 + m * 16 + lr) * 32 + lg * 8]);
#pragma unroll
    for (int n = 0; n < 4; ++n)
      bfr[n] = *reinterpret_cast<const short8*>(&Bs[(wc * 64 + n * 16 + lr) * 32 + lg * 8]);
#pragma unroll
    for (int m = 0; m < 4; ++m)
#pragma unroll
      for (int n = 0; n < 4; ++n)
        acc[m][n] = mfma16(af[m], bfr[n], acc[m][n]);
    __syncthreads();
  }

#pragma unroll
  for (int m = 0; m < 4; ++m) {
#pragma unroll
    for (int n = 0; n < 4; ++n) {
#pragma unroll
      for (int r = 0; r < 4; ++r) {
        int row = m0 + wr * 64 + m * 16 + lg * 4 + r;   // p
        int col = n0 + wc * 64 + n * 16 + lr;           // n
        float v = acc[m][n][r];
        if (MODE == 0) {
          u16* dst = (u16*)C;
          dst[(size_t)(bs * Ic + (col >> 6)) * (Pc * Hc) + (size_t)row * Hc + (col & 63)] = f2bf(v);
        } else if (MODE == 1) {
          u16* dst = (u16*)C;
          dst[(size_t)(bs * Ic + (col >> 6)) * (Pc * Hc) + (size_t)(col & 63) * Pc + row] = f2bf(v);
        } else {
          float* dst = (float*)C;
          dst[(size_t)bs * (Pc * Dc) + (size_t)row * Dc + col] = v;
        }
      }
    }
  }
}

// ---------------- flash attention per head ----------------
// Q,K: bf16 [head][p][h]; VT: bf16 [head][h][p]; Z out: bf16 [bs][q][i*64+h]
// grid (P/64, B*S*I); 4 waves/block, each wave owns 16 q-rows.
__global__ __launch_bounds__(256)
void attn_kernel(const u16* __restrict__ Q, const u16* __restrict__ K,
                 const u16* __restrict__ VT, u16* __restrict__ Z) {
  __shared__ u16 Pb[4][16 * 32];
  const int tid = threadIdx.x;
  const int lane = tid & 63, wv = tid >> 6;
  const int lr = lane & 15, lg = lane >> 4;
  const int head = blockIdx.y;
  const int bs = head >> 4, ih = head & 15;
  const int q0 = blockIdx.x * 64 + wv * 16;
  const u16* Qh = Q + (size_t)head * (Pc * Hc);
  const u16* Kh = K + (size_t)head * (Pc * Hc);
  const u16* Vh = VT + (size_t)head * (Pc * Hc);

  short8 qf[2];
  qf[0] = *reinterpret_cast<const short8*>(&Qh[(q0 + lr) * Hc + lg * 8]);
  qf[1] = *reinterpret_cast<const short8*>(&Qh[(q0 + lr) * Hc + 32 + lg * 8]);

  f32x4 zacc[4] = {};
  float mrun[4] = {-INFINITY, -INFINITY, -INFINITY, -INFINITY};
  float lrun[4] = {0.f, 0.f, 0.f, 0.f};
  const int pend = blockIdx.x * 64 + 64;   // block-uniform causal bound

  for (int p0 = 0; p0 < pend; p0 += 32) {
    // scores S[16q x 32p] = Q K^T  (two 16-col sub-tiles)
    f32x4 s[2];
#pragma unroll
    for (int sub = 0; sub < 2; ++sub) {
      f32x4 a = {};
#pragma unroll
      for (int ks = 0; ks < 2; ++ks) {
        short8 kf = *reinterpret_cast<const short8*>(
            &Kh[(size_t)(p0 + sub * 16 + lr) * Hc + ks * 32 + lg * 8]);
        a = mfma16(qf[ks], kf, a);
      }
      s[sub] = a;
    }
    // mask (p<=q allowed; masked = -1e10/8 like ref), scale 1/sqrt(64)
    float pv0[4], pv1[4], tmax[4];
#pragma unroll
    for (int r = 0; r < 4; ++r) {
      int qrow = q0 + lg * 4 + r;
      float v0 = (p0 + lr)      <= qrow ? s[0][r] * 0.125f : -1.25e9f;
      float v1 = (p0 + 16 + lr) <= qrow ? s[1][r] * 0.125f : -1.25e9f;
      pv0[r] = v0; pv1[r] = v1;
      tmax[r] = fmaxf(v0, v1);
    }
#pragma unroll
    for (int off = 1; off < 16; off <<= 1)
#pragma unroll
      for (int r = 0; r < 4; ++r)
        tmax[r] = fmaxf(tmax[r], __shfl_xor(tmax[r], off, 64));
    float scal[4], rsum[4];
#pragma unroll
    for (int r = 0; r < 4; ++r) {
      float mnew = fmaxf(mrun[r], tmax[r]);
      scal[r] = __expf(mrun[r] - mnew);   // first tile: exp(-inf)=0
      mrun[r] = mnew;
      float e0 = __expf(pv0[r] - mnew);
      float e1 = __expf(pv1[r] - mnew);
      pv0[r] = e0; pv1[r] = e1;
      rsum[r] = e0 + e1;
    }
#pragma unroll
    for (int off = 1; off < 16; off <<= 1)
#pragma unroll
      for (int r = 0; r < 4; ++r)
        rsum[r] += __shfl_xor(rsum[r], off, 64);
#pragma unroll
    for (int r = 0; r < 4; ++r) {
      lrun[r] = lrun[r] * scal[r] + rsum[r];
#pragma unroll
      for (int n = 0; n < 4; ++n) zacc[n][r] *= scal[r];
    }
    // bounce P through LDS: score layout (row=lg*4+r, col=lr) -> A-frag (row=lr, k=lg*8+j)
    __syncthreads();   // WAR vs previous iteration's reads
#pragma unroll
    for (int r = 0; r < 4; ++r) {
      Pb[wv][(lg * 4 + r) * 32 + lr]      = f2bf(pv0[r]);
      Pb[wv][(lg * 4 + r) * 32 + 16 + lr] = f2bf(pv1[r]);
    }
    __syncthreads();   // RAW
    short8 pa = *reinterpret_cast<const short8*>(&Pb[wv][lr * 32 + lg * 8]);
#pragma unroll
    for (int n = 0; n < 4; ++n) {
      short8 vf = *reinterpret_cast<const short8*>(
          &Vh[(size_t)(n * 16 + lr) * Pc + p0 + lg * 8]);
      zacc[n] = mfma16(pa, vf, zacc[n]);
    }
  }

  u16* Zb = Z + (size_t)bs * (Pc * Ic * Hc) + ih * Hc;
#pragma unroll
  for (int r = 0; r < 4; ++r) {
    float inv = 1.0f / lrun[r];
    int qrow = q0 + lg * 4 + r;
#pragma unroll
    for (int n = 0; n < 4; ++n)
      Zb[(size_t)qrow * (Ic * Hc) + n * 16 + lr] = f2bf(zacc[n][r] * inv);
  }
}

// ---------------- launch ----------------
extern "C" void kernel_launch(void* const* d_in, const int* in_sizes, int n_in,
                              void* d_out, int out_size, void* d_ws, size_t ws_size,
                              hipStream_t stream) {
  const float* x  = (const float*)d_in[0];
  const float* wk = (const float*)d_in[1];
  const float* wq = (const float*)d_in[2];
  const float* wv = (const float*)d_in[3];
  const float* wo = (const float*)d_in[4];

  // ws carve (bytes) — total 80 MB:
  // xbf 0..16M | wkb 16M | wqb 20M | wvb 24M | wob 28M | q 32M | k 48M | vT 64M..80M
  // z aliases xbf (x dead after QKV GEMMs).
  char* w = (char*)d_ws;
  u16* xbf = (u16*)w;
  u16* wkb = (u16*)(w + 16777216);
  u16* wqb = (u16*)(w + 16777216 + 1 * 4194304);
  u16* wvb = (u16*)(w + 16777216 + 2 * 4194304);
  u16* wob = (u16*)(w + 16777216 + 3 * 4194304);
  u16* qws = (u16*)(w + 16777216 + 4 * 4194304);
  u16* kws = qws + 8388608;
  u16* vtw = kws + 8388608;
  u16* zws = xbf;   // alias

  cvt_kernel<<<1024, 256, 0, stream>>>(x,  xbf, (Bc * Sc * Pc * Dc) / 4);
  cvt_kernel<<<512, 256, 0, stream>>>(wk, wkb, (Sc * Ic * Hc * Dc) / 4);
  cvt_kernel<<<512, 256, 0, stream>>>(wq, wqb, (Sc * Ic * Hc * Dc) / 4);
  cvt_kernel<<<512, 256, 0, stream>>>(wv, wvb, (Sc * Ic * Hc * Dc) / 4);
  cvt_kernel<<<512, 256, 0, stream>>>(wo, wob, (Sc * Dc * Ic * Hc) / 4);

  dim3 g(8, 8, Bc * Sc);
  gemm_bt<0><<<g, 256, 0, stream>>>(xbf, wqb, qws);
  gemm_bt<0><<<g, 256, 0, stream>>>(xbf, wkb, kws);
  gemm_bt<1><<<g, 256, 0, stream>>>(xbf, wvb, vtw);

  attn_kernel<<<dim3(Pc / 64, Bc * Sc * Ic), 256, 0, stream>>>(qws, kws, vtw, zws);

  gemm_bt<2><<<g, 256, 0, stream>>>(zws, wob, d_out);
}

// Round 2
// 259.837 us; speedup vs baseline: 1.3881x; 1.3881x over previous
//
#include <hip/hip_runtime.h>
#include <hip/hip_bf16.h>
#include <cmath>

// Problem constants (fixed by the reference):
// x: [B=4,S=2,P=1024,D=1024] f32; W_{K,Q,V}: [S,I=16,H=64,D] f32; W_O: [S,D,I*H] f32
// out: [B,S,P,D] f32
#define Bc 4
#define Sc 2
#define Pc 1024
#define Dc 1024
#define Ic 16
#define Hc 64

typedef unsigned short u16;
typedef __attribute__((ext_vector_type(8))) short short8;
typedef __attribute__((ext_vector_type(8))) __bf16 bf16x8;
typedef __attribute__((ext_vector_type(4))) float f32x4;

__device__ __forceinline__ u16 f2bf(float f) {
  union { float f; unsigned u; } c; c.f = f;
  unsigned u = c.u;
  u += 0x7fffu + ((u >> 16) & 1u);   // RNE
  return (u16)(u >> 16);
}

// pack two f32 -> bf16x2 in one instruction (RNE)
__device__ __forceinline__ unsigned cvtpk_bf16(float lo, float hi) {
  unsigned r;
  asm("v_cvt_pk_bf16_f32 %0, %1, %2" : "=v"(r) : "v"(lo), "v"(hi));
  return r;
}

__device__ __forceinline__ f32x4 mfma16(short8 a, short8 b, f32x4 c) {
  return __builtin_amdgcn_mfma_f32_16x16x32_bf16(
      __builtin_bit_cast(bf16x8, a), __builtin_bit_cast(bf16x8, b), c, 0, 0, 0);
}

__device__ __forceinline__ void load_lds16(const u16* g, u16* l) {
  __builtin_amdgcn_global_load_lds(
      (const __attribute__((address_space(1))) void*)g,
      (__attribute__((address_space(3))) void*)l, 16, 0, 0);
}

// ---------------- fp32 -> bf16 convert ----------------
__global__ void cvt_kernel(const float* __restrict__ src, u16* __restrict__ dst, int n4) {
  int i = blockIdx.x * blockDim.x + threadIdx.x;
  int stride = gridDim.x * blockDim.x;
  for (; i < n4; i += stride) {
    float4 v = reinterpret_cast<const float4*>(src)[i];
    ushort4 o;
    o.x = f2bf(v.x); o.y = f2bf(v.y); o.z = f2bf(v.z); o.w = f2bf(v.w);
    reinterpret_cast<ushort4*>(dst)[i] = o;
  }
}

// ---------------- GEMM-BT: C[M=1024,N=1024] = A[bs] * B[s]^T (K=1024) ----------------
// MODE 0: dst bf16 heads layout [bs*16 + n>>6][p][n&63]   (Q, K)
// MODE 1: dst bf16 transposed   [bs*16 + n>>6][n&63][p]   (V^T)
// MODE 2: dst f32  [bs][p][n]                              (final out)
template<int MODE>
__global__ __launch_bounds__(256)
void gemm_bt(const u16* __restrict__ A, const u16* __restrict__ Bm, void* __restrict__ C) {
  __shared__ u16 As[128 * 32];
  __shared__ u16 Bs[128 * 32];
  const int tid = threadIdx.x;
  const int lane = tid & 63;
  const int wv = tid >> 6;
  const int wr = wv >> 1, wc = wv & 1;
  const int lr = lane & 15, lg = lane >> 4;
  const int m0 = blockIdx.x * 128, n0 = blockIdx.y * 128;
  const int bs = blockIdx.z;
  const u16* Ab = A + (size_t)bs * (Pc * Dc);
  const u16* Bb = Bm + (size_t)(bs & 1) * (1024 * 1024);
  f32x4 acc[4][4] = {};

  for (int k0 = 0; k0 < 1024; k0 += 32) {
#pragma unroll
    for (int it = 0; it < 2; ++it) {
      int slot = it * 256 + tid;
      int row = slot >> 2;
      int c8 = (slot & 3) << 3;
      load_lds16(Ab + (size_t)(m0 + row) * 1024 + k0 + c8, As + slot * 8);
      load_lds16(Bb + (size_t)(n0 + row) * 1024 + k0 + c8, Bs + slot * 8);
    }
    __syncthreads();   // drains vmcnt -> LDS staged
    short8 af[4], bfr[4];
#pragma unroll
    for (int m = 0; m < 4; ++m)
      af[m] = *reinterpret_cast<const short8*>(&As[(wr * 64 + m * 16 + lr) * 32 + lg * 8]);
#pragma unroll
    for (int n = 0; n < 4; ++n)
      bfr[n] = *reinterpret_cast<const short8*>(&Bs[(wc * 64 + n * 16 + lr) * 32 + lg * 8]);
#pragma unroll
    for (int m = 0; m < 4; ++m)
#pragma unroll
      for (int n = 0; n < 4; ++n)
        acc[m][n] = mfma16(af[m], bfr[n], acc[m][n]);
    __syncthreads();
  }

#pragma unroll
  for (int m = 0; m < 4; ++m) {
#pragma unroll
    for (int n = 0; n < 4; ++n) {
#pragma unroll
      for (int r = 0; r < 4; ++r) {
        int row = m0 + wr * 64 + m * 16 + lg * 4 + r;   // p
        int col = n0 + wc * 64 + n * 16 + lr;           // n
        float v = acc[m][n][r];
        if (MODE == 0) {
          u16* dst = (u16*)C;
          dst[(size_t)(bs * Ic + (col >> 6)) * (Pc * Hc) + (size_t)row * Hc + (col & 63)] = f2bf(v);
        } else if (MODE == 1) {
          u16* dst = (u16*)C;
          dst[(size_t)(bs * Ic + (col >> 6)) * (Pc * Hc) + (size_t)(col & 63) * Pc + row] = f2bf(v);
        } else {
          float* dst = (float*)C;
          dst[(size_t)bs * (Pc * Dc) + (size_t)row * Dc + col] = v;
        }
      }
    }
  }
}

// ---------------- flash attention, swapped-QK^T, wave-autonomous ----------------
// Q,K: bf16 [head][p][h]; VT: bf16 [head][h][p]; Z out: bf16 [bs][q][i*64+h]
// grid (128 heads, 16 q-groups reversed); 4 waves/block = 4 q-tiles of the SAME
// head (shared K/V tile -> L1 hits). Each wave: 16 q rows, KVBLK=64, no barriers.
// Swapped mfma(K,Q): S^T tile, lane owns q = lane&15; kv = sub*16 + (lane>>4)*4 + reg.
__global__ __launch_bounds__(256)
void attn_kernel(const u16* __restrict__ Q, const u16* __restrict__ K,
                 const u16* __restrict__ VT, u16* __restrict__ Z) {
  __shared__ __align__(16) u16 Pb[4][16 * 72];   // per-wave private, 72 = pad for 16B-aligned rows
  const int tid = threadIdx.x;
  const int lane = tid & 63, wv = tid >> 6;
  const int lr = lane & 15, lg = lane >> 4;
  const int head = blockIdx.x;
  const int bs = head >> 4, ih = head & 15;
  const int qg = 15 - blockIdx.y;        // reversed: longest blocks launch first
  const int q0 = qg * 64 + wv * 16;
  const u16* Qh = Q + (size_t)head * (Pc * Hc);
  const u16* Kh = K + (size_t)head * (Pc * Hc);
  const u16* Vh = VT + (size_t)head * (Pc * Hc);

  // Q fragments (B-operand: col=lane&15=q, k=(lane>>4)*8+j over h)
  short8 qf[2];
  qf[0] = *reinterpret_cast<const short8*>(&Qh[(q0 + lr) * Hc + lg * 8]);
  qf[1] = *reinterpret_cast<const short8*>(&Qh[(q0 + lr) * Hc + 32 + lg * 8]);

  f32x4 zacc[4] = {};            // Z[16q x 64h]: col=lane&15=h16, row=(lane>>4)*4+r=q
  float mrun = -INFINITY;        // softmax state for q = q0 + lr (one row per lane)
  float lrun = 0.f;
  const int myq = q0 + lr;

  for (int p0 = 0; p0 <= q0; p0 += 64) {
    // ---- scores S^T[64kv x 16q] via mfma(K, Q) ----
    float pv[4][4];
    float tmax = -INFINITY;
    const bool needmask = (p0 + 63 > q0);   // wave-uniform
#pragma unroll
    for (int sub = 0; sub < 4; ++sub) {
      const u16* kp = &Kh[(size_t)(p0 + sub * 16 + lr) * Hc + lg * 8];
      short8 k0 = *reinterpret_cast<const short8*>(kp);
      short8 k1 = *reinterpret_cast<const short8*>(kp + 32);
      f32x4 a = mfma16(k0, qf[0], (f32x4){0.f, 0.f, 0.f, 0.f});
      a = mfma16(k1, qf[1], a);
      if (needmask) {
#pragma unroll
        for (int r = 0; r < 4; ++r) {
          int kv = p0 + sub * 16 + lg * 4 + r;
          float v = (kv <= myq) ? a[r] * 0.125f : -1.25e9f;   // -1e10/sqrt(64)
          pv[sub][r] = v;
          tmax = fmaxf(tmax, v);
        }
      } else {
#pragma unroll
        for (int r = 0; r < 4; ++r) {
          float v = a[r] * 0.125f;
          pv[sub][r] = v;
          tmax = fmaxf(tmax, v);
        }
      }
    }
    // ---- online softmax (per-lane row; 2 shuffles to combine lane-groups) ----
    tmax = fmaxf(tmax, __shfl_xor(tmax, 16, 64));
    tmax = fmaxf(tmax, __shfl_xor(tmax, 32, 64));
    float mnew = fmaxf(mrun, tmax);
    float scal = __expf(mrun - mnew);      // first tile: exp(-inf) = 0
    mrun = mnew;
    float rsum = 0.f;
#pragma unroll
    for (int sub = 0; sub < 4; ++sub)
#pragma unroll
      for (int r = 0; r < 4; ++r) {
        float e = __expf(pv[sub][r] - mnew);
        pv[sub][r] = e;
        rsum += e;
      }
    rsum += __shfl_xor(rsum, 16, 64);
    rsum += __shfl_xor(rsum, 32, 64);
    lrun = lrun * scal + rsum;
    // broadcast scal to zacc's row owners (zacc row q = lg*4+r lives at lane lr=q)
    float sc[4];
#pragma unroll
    for (int r = 0; r < 4; ++r) sc[r] = __shfl(scal, lg * 4 + r, 64);
#pragma unroll
    for (int n = 0; n < 4; ++n)
#pragma unroll
      for (int r = 0; r < 4; ++r) zacc[n][r] *= sc[r];
    // ---- P -> LDS (row q=lr, col kv; packed pairs), then read as A-fragment ----
    u16* Pw = Pb[wv];
#pragma unroll
    for (int sub = 0; sub < 4; ++sub) {
      *reinterpret_cast<unsigned*>(&Pw[lr * 72 + sub * 16 + lg * 4 + 0]) =
          cvtpk_bf16(pv[sub][0], pv[sub][1]);
      *reinterpret_cast<unsigned*>(&Pw[lr * 72 + sub * 16 + lg * 4 + 2]) =
          cvtpk_bf16(pv[sub][2], pv[sub][3]);
    }
    short8 pa0 = *reinterpret_cast<const short8*>(&Pw[lr * 72 + lg * 8]);
    short8 pa1 = *reinterpret_cast<const short8*>(&Pw[lr * 72 + 32 + lg * 8]);
    // ---- PV: Z += P * V  (B-operand from VT: col=lane&15=h, k=kv contiguous) ----
#pragma unroll
    for (int n = 0; n < 4; ++n) {
      const u16* vp = &Vh[(size_t)(n * 16 + lr) * Pc + p0 + lg * 8];
      short8 v0 = *reinterpret_cast<const short8*>(vp);
      short8 v1 = *reinterpret_cast<const short8*>(vp + 32);
      zacc[n] = mfma16(pa0, v0, zacc[n]);
      zacc[n] = mfma16(pa1, v1, zacc[n]);
    }
  }

  // ---- epilogue: divide by l (broadcast from softmax lanes), store ----
  float inv = 1.0f / lrun;
  float invr[4];
#pragma unroll
  for (int r = 0; r < 4; ++r) invr[r] = __shfl(inv, lg * 4 + r, 64);
  u16* Zb = Z + (size_t)bs * (Pc * Ic * Hc) + ih * Hc;
#pragma unroll
  for (int r = 0; r < 4; ++r) {
    int qrow = q0 + lg * 4 + r;
#pragma unroll
    for (int n = 0; n < 4; ++n)
      Zb[(size_t)qrow * (Ic * Hc) + n * 16 + lr] = f2bf(zacc[n][r] * invr[r]);
  }
}

// ---------------- launch ----------------
extern "C" void kernel_launch(void* const* d_in, const int* in_sizes, int n_in,
                              void* d_out, int out_size, void* d_ws, size_t ws_size,
                              hipStream_t stream) {
  const float* x  = (const float*)d_in[0];
  const float* wk = (const float*)d_in[1];
  const float* wq = (const float*)d_in[2];
  const float* wv = (const float*)d_in[3];
  const float* wo = (const float*)d_in[4];

  // ws carve (bytes) — total 80 MB:
  // xbf 0..16M | wkb 16M | wqb 20M | wvb 24M | wob 28M | q 32M | k 48M | vT 64M..80M
  // z aliases xbf (x dead after QKV GEMMs).
  char* w = (char*)d_ws;
  u16* xbf = (u16*)w;
  u16* wkb = (u16*)(w + 16777216);
  u16* wqb = (u16*)(w + 16777216 + 1 * 4194304);
  u16* wvb = (u16*)(w + 16777216 + 2 * 4194304);
  u16* wob = (u16*)(w + 16777216 + 3 * 4194304);
  u16* qws = (u16*)(w + 16777216 + 4 * 4194304);
  u16* kws = qws + 8388608;
  u16* vtw = kws + 8388608;
  u16* zws = xbf;   // alias

  cvt_kernel<<<1024, 256, 0, stream>>>(x,  xbf, (Bc * Sc * Pc * Dc) / 4);
  cvt_kernel<<<512, 256, 0, stream>>>(wk, wkb, (Sc * Ic * Hc * Dc) / 4);
  cvt_kernel<<<512, 256, 0, stream>>>(wq, wqb, (Sc * Ic * Hc * Dc) / 4);
  cvt_kernel<<<512, 256, 0, stream>>>(wv, wvb, (Sc * Ic * Hc * Dc) / 4);
  cvt_kernel<<<512, 256, 0, stream>>>(wo, wob, (Sc * Dc * Ic * Hc) / 4);

  dim3 g(8, 8, Bc * Sc);
  gemm_bt<0><<<g, 256, 0, stream>>>(xbf, wqb, qws);
  gemm_bt<0><<<g, 256, 0, stream>>>(xbf, wkb, kws);
  gemm_bt<1><<<g, 256, 0, stream>>>(xbf, wvb, vtw);

  attn_kernel<<<dim3(128, 16), 256, 0, stream>>>(qws, kws, vtw, zws);

  gemm_bt<2><<<g, 256, 0, stream>>>(zws, wob, d_out);
}

// Round 3
// 202.625 us; speedup vs baseline: 1.7800x; 1.2824x over previous
//
#include <hip/hip_runtime.h>
#include <hip/hip_bf16.h>
#include <cmath>

// x: [B=4,S=2,P=1024,D=1024] f32; W_{K,Q,V}: [S,I=16,H=64,D] f32; W_O: [S,D,I*H] f32
// out: [B,S,P,D] f32
#define Bc 4
#define Sc 2
#define Pc 1024
#define Dc 1024
#define Ic 16
#define Hc 64

typedef unsigned short u16;
typedef unsigned int u32;
typedef __attribute__((ext_vector_type(8))) short short8;
typedef __attribute__((ext_vector_type(8))) __bf16 bf16x8;
typedef __attribute__((ext_vector_type(4))) float f32x4;

__device__ __forceinline__ u16 f2bf(float f) {
  union { float f; unsigned u; } c; c.f = f;
  unsigned u = c.u;
  u += 0x7fffu + ((u >> 16) & 1u);   // RNE
  return (u16)(u >> 16);
}

__device__ __forceinline__ u32 cvtpk_bf16(float lo, float hi) {
  u32 r;
  asm("v_cvt_pk_bf16_f32 %0, %1, %2" : "=v"(r) : "v"(lo), "v"(hi));
  return r;
}

__device__ __forceinline__ f32x4 mfma16(short8 a, short8 b, f32x4 c) {
  return __builtin_amdgcn_mfma_f32_16x16x32_bf16(
      __builtin_bit_cast(bf16x8, a), __builtin_bit_cast(bf16x8, b), c, 0, 0, 0);
}

__device__ __forceinline__ void load_lds16(const u16* g, u16* l) {
  __builtin_amdgcn_global_load_lds(
      (const __attribute__((address_space(1))) void*)g,
      (__attribute__((address_space(3))) void*)l, 16, 0, 0);
}

// ---------------- fp32 -> bf16 convert ----------------
__global__ void cvt_kernel(const float* __restrict__ src, u16* __restrict__ dst, int n4) {
  int i = blockIdx.x * blockDim.x + threadIdx.x;
  int stride = gridDim.x * blockDim.x;
  for (; i < n4; i += stride) {
    float4 v = reinterpret_cast<const float4*>(src)[i];
    ushort4 o;
    o.x = f2bf(v.x); o.y = f2bf(v.y); o.z = f2bf(v.z); o.w = f2bf(v.w);
    reinterpret_cast<ushort4*>(dst)[i] = o;
  }
}

// ---------------- GEMM-BT: C[1024,1024] = A[bs] * B[s]^T (K=1024) ----------------
// MODE 0: dst bf16 heads layout [bs*16 + n>>6][p][n&63]   (Q, K)
// MODE 1: dst bf16 transposed   [bs*16 + n>>6][n&63][p]   (V^T)
// MODE 2: dst f32  [bs][p][n]                              (final out)
// oscale multiplies the result before rounding (0.125 for Q: exact pow2).
template<int MODE>
__global__ __launch_bounds__(256)
void gemm_bt(const u16* __restrict__ A, const u16* __restrict__ Bm, void* __restrict__ C,
             float oscale) {
  __shared__ u16 As[128 * 32];
  __shared__ u16 Bs[128 * 32];
  const int tid = threadIdx.x;
  const int lane = tid & 63;
  const int wv = tid >> 6;
  const int wr = wv >> 1, wc = wv & 1;
  const int lr = lane & 15, lg = lane >> 4;
  const int m0 = blockIdx.x * 128, n0 = blockIdx.y * 128;
  const int bs = blockIdx.z;
  const u16* Ab = A + (size_t)bs * (Pc * Dc);
  const u16* Bb = Bm + (size_t)(bs & 1) * (1024 * 1024);
  f32x4 acc[4][4] = {};

  for (int k0 = 0; k0 < 1024; k0 += 32) {
#pragma unroll
    for (int it = 0; it < 2; ++it) {
      int slot = it * 256 + tid;
      int row = slot >> 2;
      int c8 = (slot & 3) << 3;
      load_lds16(Ab + (size_t)(m0 + row) * 1024 + k0 + c8, As + slot * 8);
      load_lds16(Bb + (size_t)(n0 + row) * 1024 + k0 + c8, Bs + slot * 8);
    }
    __syncthreads();
    short8 af[4], bfr[4];
#pragma unroll
    for (int m = 0; m < 4; ++m)
      af[m] = *reinterpret_cast<const short8*>(&As[(wr * 64 + m * 16 + lr) * 32 + lg * 8]);
#pragma unroll
    for (int n = 0; n < 4; ++n)
      bfr[n] = *reinterpret_cast<const short8*>(&Bs[(wc * 64 + n * 16 + lr) * 32 + lg * 8]);
#pragma unroll
    for (int m = 0; m < 4; ++m)
#pragma unroll
      for (int n = 0; n < 4; ++n)
        acc[m][n] = mfma16(af[m], bfr[n], acc[m][n]);
    __syncthreads();
  }

#pragma unroll
  for (int m = 0; m < 4; ++m) {
#pragma unroll
    for (int n = 0; n < 4; ++n) {
#pragma unroll
      for (int r = 0; r < 4; ++r) {
        int row = m0 + wr * 64 + m * 16 + lg * 4 + r;   // p
        int col = n0 + wc * 64 + n * 16 + lr;           // n
        float v = acc[m][n][r] * oscale;
        if (MODE == 0) {
          u16* dst = (u16*)C;
          dst[(size_t)(bs * Ic + (col >> 6)) * (Pc * Hc) + (size_t)row * Hc + (col & 63)] = f2bf(v);
        } else if (MODE == 1) {
          u16* dst = (u16*)C;
          dst[(size_t)(bs * Ic + (col >> 6)) * (Pc * Hc) + (size_t)(col & 63) * Pc + row] = f2bf(v);
        } else {
          float* dst = (float*)C;
          dst[(size_t)bs * (Pc * Dc) + (size_t)row * Dc + col] = v;
        }
      }
    }
  }
}

// ---------------- flash attention v3 ----------------
// Q,K: bf16 [head][p][h] (Q pre-scaled by 0.125); VT: bf16 [head][h][p];
// Z: bf16 [bs][q][i*64+h].
// grid (128 heads, 8 q-groups reversed), 256 thr. Block covers 128 q rows;
// wave wv owns rows [qg*128+wv*32, +32) as two 16-row subtiles.
// K/V staged per block in double-buffered XOR-swizzled LDS (T2 via pre-swizzled
// global source, rule 21); swapped mfma(K,Q) -> lane owns q-row; defer-max (T13).
// LDS: 2*8K (K) + 2*8K (V) + 4*2K (P) = 40960 B -> exactly 4 blocks/CU.
__global__ __launch_bounds__(256, 4)
void attn_kernel(const u16* __restrict__ Q, const u16* __restrict__ K,
                 const u16* __restrict__ VT, u16* __restrict__ Z) {
  __shared__ __align__(16) u16 Kt[2][64 * 64];
  __shared__ __align__(16) u16 Vt[2][64 * 64];
  __shared__ __align__(16) u16 Pb[4][16 * 64];
  const int tid = threadIdx.x;
  const int lane = tid & 63, wv = tid >> 6;
  const int lr = lane & 15, lg = lane >> 4;
  const int head = blockIdx.x;
  const int bs = head >> 4, ih = head & 15;
  const int qg = 7 - (int)blockIdx.y;      // longest blocks first
  const int qbase = qg * 128 + wv * 32;
  const u16* Qh = Q + (size_t)head * (Pc * Hc);
  const u16* Kh = K + (size_t)head * (Pc * Hc);
  const u16* Vh = VT + (size_t)head * (Pc * Hc);
  const int ntiles = 2 * qg + 2;

  // Q fragments for the two 16-row subtiles (B-operand: col=lr=q, k=lg*8+j over h)
  short8 qf[2][2];
#pragma unroll
  for (int st = 0; st < 2; ++st) {
    const u16* qp = &Qh[(size_t)(qbase + st * 16 + lr) * Hc + lg * 8];
    qf[st][0] = *reinterpret_cast<const short8*>(qp);
    qf[st][1] = *reinterpret_cast<const short8*>(qp + 32);
  }

  f32x4 zacc[2][4] = {};          // per subtile: Z[16q x 64h], col=lr=h16, row=lg*4+r=q
  float mrun[2] = {-INFINITY, -INFINITY};
  float lrun[2] = {0.f, 0.f};
  const int swl = (lr & 7) << 4;  // P-buffer swizzle for this lane's q-row

  // stage(t, buf): 512 16B-chunks per tile, 2 per thread per tensor.
  // LDS[r][c] chunk holds global chunk c^(r&7) of row r (inverse-swizzled source).
#define STAGE(t, buf)                                                          \
  {                                                                            \
    _Pragma("unroll")                                                          \
    for (int i = 0; i < 2; ++i) {                                              \
      int cid = wv * 128 + i * 64 + lane;                                      \
      int r = cid >> 3;                                                        \
      int sc = (cid & 7) ^ (r & 7);                                            \
      load_lds16(Kh + (size_t)((t) * 64 + r) * Hc + sc * 8, &Kt[buf][cid * 8]);\
      load_lds16(Vh + (size_t)r * Pc + (t) * 64 + sc * 8, &Vt[buf][cid * 8]);  \
    }                                                                          \
  }

  STAGE(0, 0)
  __syncthreads();   // compiler drains vmcnt before barrier -> tile 0 staged

  for (int t = 0; t < ntiles; ++t) {
    const int cur = t & 1;
    if (t + 1 < ntiles) STAGE(t + 1, cur ^ 1)

    // ---- QK^T (swapped): S^T[64kv x 16q] per subtile, K-frags shared ----
    const char* Kc = (const char*)Kt[cur];
    f32x4 aA[4], aB[4];
#pragma unroll
    for (int sub = 0; sub < 4; ++sub) {
      int row = sub * 16 + lr;
      int b0 = row * 128 + ((lg ^ (row & 7)) << 4);
      short8 k0 = *reinterpret_cast<const short8*>(Kc + b0);
      short8 k1 = *reinterpret_cast<const short8*>(Kc + (b0 ^ 64));
      f32x4 z4 = {0.f, 0.f, 0.f, 0.f};
      aA[sub] = mfma16(k1, qf[0][1], mfma16(k0, qf[0][0], z4));
      aB[sub] = mfma16(k1, qf[1][1], mfma16(k0, qf[1][0], z4));
    }

    // ---- per-subtile softmax + P-bounce -> A-fragments ----
    short8 pa[2][2];
#pragma unroll
    for (int st = 0; st < 2; ++st) {
      f32x4* a = (st == 0) ? aA : aB;
      const int q0s = qbase + st * 16;
      if (t * 64 + 63 > q0s) {          // wave-uniform mask branch
        const int myq = q0s + lr;
#pragma unroll
        for (int sub = 0; sub < 4; ++sub)
#pragma unroll
          for (int r = 0; r < 4; ++r) {
            int kv = t * 64 + sub * 16 + lg * 4 + r;
            a[sub][r] = (kv <= myq) ? a[sub][r] : -1.25e9f;
          }
      }
      float tmax = -INFINITY;
#pragma unroll
      for (int sub = 0; sub < 4; ++sub)
#pragma unroll
        for (int r = 0; r < 4; ++r) tmax = fmaxf(tmax, a[sub][r]);
      tmax = fmaxf(tmax, __shfl_xor(tmax, 16, 64));
      tmax = fmaxf(tmax, __shfl_xor(tmax, 32, 64));
      float mr = mrun[st];
      if (!__all(tmax - mr <= 8.0f)) {   // defer-max: rescale only on real growth
        float mnew = fmaxf(mr, tmax);
        float scal = __expf(mr - mnew);  // first tile: exp(-inf)=0
        float sc0 = __shfl(scal, lg * 4 + 0, 64);
        float sc1 = __shfl(scal, lg * 4 + 1, 64);
        float sc2 = __shfl(scal, lg * 4 + 2, 64);
        float sc3 = __shfl(scal, lg * 4 + 3, 64);
#pragma unroll
        for (int n = 0; n < 4; ++n) {
          zacc[st][n][0] *= sc0; zacc[st][n][1] *= sc1;
          zacc[st][n][2] *= sc2; zacc[st][n][3] *= sc3;
        }
        lrun[st] *= scal;
        mrun[st] = mnew; mr = mnew;
      }
      float rsum = 0.f;
#pragma unroll
      for (int sub = 0; sub < 4; ++sub)
#pragma unroll
        for (int r = 0; r < 4; ++r) {
          float e = __expf(a[sub][r] - mr);
          a[sub][r] = e;
          rsum += e;
        }
      rsum += __shfl_xor(rsum, 16, 64);
      rsum += __shfl_xor(rsum, 32, 64);
      lrun[st] += rsum;
      // bounce P (row q=lr) through swizzled per-wave LDS, re-read as A-frag
      char* Pw = (char*)Pb[wv];
#pragma unroll
      for (int sub = 0; sub < 4; ++sub) {
        *reinterpret_cast<u32*>(Pw + lr * 128 + ((sub * 32 + lg * 8 + 0) ^ swl)) =
            cvtpk_bf16(a[sub][0], a[sub][1]);
        *reinterpret_cast<u32*>(Pw + lr * 128 + ((sub * 32 + lg * 8 + 4) ^ swl)) =
            cvtpk_bf16(a[sub][2], a[sub][3]);
      }
      int rb = lr * 128 + ((lg * 16) ^ swl);
      pa[st][0] = *reinterpret_cast<const short8*>(Pw + rb);
      pa[st][1] = *reinterpret_cast<const short8*>(Pw + (rb ^ 64));
    }

    // ---- PV: Z += P * V, V-frags shared between subtiles ----
    const char* Vc = (const char*)Vt[cur];
#pragma unroll
    for (int ks = 0; ks < 2; ++ks)
#pragma unroll
      for (int n = 0; n < 4; ++n) {
        int row = n * 16 + lr;
        int vb = row * 128 + (((ks * 4 + lg) ^ (row & 7)) << 4);
        short8 v = *reinterpret_cast<const short8*>(Vc + vb);
        zacc[0][n] = mfma16(pa[0][ks], v, zacc[0][n]);
        zacc[1][n] = mfma16(pa[1][ks], v, zacc[1][n]);
      }

    __syncthreads();   // all waves done with buf cur; next stage may overwrite
  }

  // ---- epilogue ----
  u16* Zb = Z + (size_t)bs * (Pc * Ic * Hc) + ih * Hc;
#pragma unroll
  for (int st = 0; st < 2; ++st) {
    float inv = 1.0f / lrun[st];
    float iv[4];
#pragma unroll
    for (int r = 0; r < 4; ++r) iv[r] = __shfl(inv, lg * 4 + r, 64);
    const int q0s = qbase + st * 16;
#pragma unroll
    for (int r = 0; r < 4; ++r) {
      int qrow = q0s + lg * 4 + r;
#pragma unroll
      for (int n = 0; n < 4; ++n)
        Zb[(size_t)qrow * (Ic * Hc) + n * 16 + lr] = f2bf(zacc[st][n][r] * iv[r]);
    }
  }
#undef STAGE
}

// ---------------- launch ----------------
extern "C" void kernel_launch(void* const* d_in, const int* in_sizes, int n_in,
                              void* d_out, int out_size, void* d_ws, size_t ws_size,
                              hipStream_t stream) {
  const float* x  = (const float*)d_in[0];
  const float* wk = (const float*)d_in[1];
  const float* wq = (const float*)d_in[2];
  const float* wv = (const float*)d_in[3];
  const float* wo = (const float*)d_in[4];

  char* w = (char*)d_ws;
  u16* xbf = (u16*)w;
  u16* wkb = (u16*)(w + 16777216);
  u16* wqb = (u16*)(w + 16777216 + 1 * 4194304);
  u16* wvb = (u16*)(w + 16777216 + 2 * 4194304);
  u16* wob = (u16*)(w + 16777216 + 3 * 4194304);
  u16* qws = (u16*)(w + 16777216 + 4 * 4194304);
  u16* kws = qws + 8388608;
  u16* vtw = kws + 8388608;
  u16* zws = xbf;   // alias: x dead after QKV GEMMs

  cvt_kernel<<<1024, 256, 0, stream>>>(x,  xbf, (Bc * Sc * Pc * Dc) / 4);
  cvt_kernel<<<512, 256, 0, stream>>>(wk, wkb, (Sc * Ic * Hc * Dc) / 4);
  cvt_kernel<<<512, 256, 0, stream>>>(wq, wqb, (Sc * Ic * Hc * Dc) / 4);
  cvt_kernel<<<512, 256, 0, stream>>>(wv, wvb, (Sc * Ic * Hc * Dc) / 4);
  cvt_kernel<<<512, 256, 0, stream>>>(wo, wob, (Sc * Dc * Ic * Hc) / 4);

  dim3 g(8, 8, Bc * Sc);
  gemm_bt<0><<<g, 256, 0, stream>>>(xbf, wqb, qws, 0.125f);  // Q pre-scaled (exact)
  gemm_bt<0><<<g, 256, 0, stream>>>(xbf, wkb, kws, 1.0f);
  gemm_bt<1><<<g, 256, 0, stream>>>(xbf, wvb, vtw, 1.0f);

  attn_kernel<<<dim3(128, 8), 256, 0, stream>>>(qws, kws, vtw, zws);

  gemm_bt<2><<<g, 256, 0, stream>>>(zws, wob, d_out, 1.0f);
}